// Round 17
// baseline (407.819 us; speedup 1.0000x reference)
//
#include <hip/hip_runtime.h>

// Problem constants
#define BB 16
#define SS 1024
#define DD 768

typedef _Float16 f16x4 __attribute__((ext_vector_type(4)));
typedef _Float16 f16x8 __attribute__((ext_vector_type(8)));
typedef float f32x4 __attribute__((ext_vector_type(4)));

__device__ __forceinline__ void gload_lds16(const void* g, void* l) {
  __builtin_amdgcn_global_load_lds(
      (const __attribute__((address_space(1))) unsigned int*)g,
      (__attribute__((address_space(3))) unsigned int*)l, 16, 0, 0);
}

// ---------------------------------------------------------------------------
// 256x128 NT GEMM: 2-blocks/CU, zero-conflict LDS (verified r14), ring-3
// slots + counted vmcnt(3) (verified r15/r16: 92->82us, MfmaUtil 26->30%).
// Pipe balance per CU (2 blocks): LDS-read ~1536 cyc/tile vs MFMA ~1240 --
// structurally LDS-issue/MFMA balanced; bigger wave-tiles would re-hit the
// 128-AGPR occupancy wall (round-11 lesson). This is the plateau kernel.
//
// LDS: 3 slots x (A 16KB + B 8KB) = 72 KiB -> still 2 blocks/CU.
// Slab layout (empirically zero-conflict): 128B pairs, element (row R,
// chunk c) at pair P=R>>1, slot q=((R&1)<<2)|(c^(P&3)).
// Staging inverse: thread t -> P=t>>3,q=t&7: src row 2P+(q>>2), chunk
// (q&3)^(P&3); dest linear t*16. Wave covers 16 full 64B segs (coalesced).
//
// Schedule per tile T: vmcnt(3) [retires T's 3 loads; T+1's stay in
// flight; vmcnt(0) only at T==NT-1]; barrier; stage T+2 -> slot (T+2)%3
// (WAR-safe: that slot's readers were tile T-1, their ds_reads retired
// before their MFMAs hence before this barrier); 8 ds_read_b128; 16 MFMA.
//
// OUTM: 0 fp32 row-major |
//       3 f16 z<2 row-major / z==2 transposed (stage-1 projections) |
//       4 f16 z<2 transposed / z==2 row-major (stage-2 projections) |
//       5 f16 row-major | 6 f16 row-major + LN partials aux[(z*24+bx*6+by)*2]
// Transposed = per-1024-row batch: C[z][(b*N+c)*1024 + s], b=row>>10.
// OUTM 3/4: grid (18,64), XCD-grouped decode (round-7 lesson).
// ---------------------------------------------------------------------------
template<int OUTM, int BIAS>
__global__ __launch_bounds__(512, 4) void gemm256(
    const _Float16* __restrict__ A, long long aB,
    const _Float16* __restrict__ Bt, long long bB,
    const float* __restrict__ bias, int biasB,
    void* __restrict__ Cv, long long cB,
    float* __restrict__ aux,
    int M, int N, int K)
{
  __shared__ __attribute__((aligned(16))) _Float16 lds[36864];  // 72 KiB
  const int t = threadIdx.x;
  int z, m0, n0;
  if (OUTM == 3 || OUTM == 4) {     // projection decode, XCD-grouped
    const int lin = blockIdx.x + 18 * blockIdx.y;  // 0..1151
    const int xcd = lin & 7, idx = lin >> 3;       // idx 0..143
    const int mt  = xcd * 8 + idx / 18;
    const int zn  = idx % 18;
    z  = zn / 6;
    n0 = (zn % 6) * 128;
    m0 = mt * 256;
  } else {
    z = blockIdx.z;
    m0 = blockIdx.x * 256;
    n0 = blockIdx.y * 128;
  }
  const _Float16* Ab = A + (size_t)z * aB;
  const _Float16* Bb = Bt + (size_t)z * bB;

  const int l = t & 63, w = t >> 6;
  const int wr = (w >> 1) * 64, wc = (w & 1) * 64;
  const int lrow = l & 15, kq = l >> 4;
  // read-side: pair-interleaved involution (measured 0 conflicts)
  const int qread = ((lrow & 1) << 2) | (kq ^ ((lrow >> 1) & 3));
  const int fragoff = (lrow >> 1) * 128 + qread * 16;

  // staging lane constants (inverse of the same involution)
  const int sp = t >> 3, sq = t & 7;
  const int srow = 2 * sp + (sq >> 2);
  const int schk = (sq & 3) ^ (sp & 3);
  const size_t ldK = (size_t)K * 2;
  const char* pA0 = (const char*)Ab + (size_t)(m0 + srow) * ldK + schk * 16;
  const char* pA1 = pA0 + (size_t)128 * ldK;
  const char* pB0 = (const char*)Bb + (size_t)(n0 + srow) * ldK + schk * 16;
  char* const ldsb = (char*)lds;
  const int dstt = t * 16;

  // stage K-tile T into ring slot sl: A (2 gloads) + B (1 gload)
  auto stg = [&](int T, int sl) {
    const char* ga0 = pA0 + (size_t)T * 64;
    const char* ga1 = pA1 + (size_t)T * 64;
    const char* gb  = pB0 + (size_t)T * 64;
    char* d = ldsb + sl * 24576 + dstt;
    gload_lds16(ga0, d);
    gload_lds16(ga1, d + 8192);
    gload_lds16(gb,  d + 16384);
  };

  f32x4 acc[4][4] = {};
  f16x8 af[4], bf[4];

  // prologue: tiles 0,1 -> slots 0,1
  stg(0, 0);
  stg(1, 1);

  const int NT = K >> 5;
  int sl = 0, slw = 2;   // read slot of T; write slot of T+2
  for (int T = 0; T < NT; ++T) {
    const char* Abase = ldsb + sl * 24576;
    const char* Bbase = Abase + 16384;

    if (T == NT - 1) asm volatile("s_waitcnt vmcnt(0)" ::: "memory");
    else             asm volatile("s_waitcnt vmcnt(3)" ::: "memory");
    __builtin_amdgcn_s_barrier();
    asm volatile("" ::: "memory");
    if (T + 2 < NT) stg(T + 2, slw);

    #pragma unroll
    for (int n = 0; n < 4; n++)
      bf[n] = *(const f16x8*)(Bbase + (wc + n * 16) * 64 + fragoff);
    #pragma unroll
    for (int mi = 0; mi < 4; mi++)
      af[mi] = *(const f16x8*)(Abase + (wr + mi * 16) * 64 + fragoff);

    __builtin_amdgcn_s_setprio(1);
    #pragma unroll
    for (int mi = 0; mi < 4; mi++)
      #pragma unroll
      for (int n = 0; n < 4; n++)
        acc[mi][n] = __builtin_amdgcn_mfma_f32_16x16x32_f16(af[mi], bf[n], acc[mi][n], 0, 0, 0);
    __builtin_amdgcn_s_setprio(0);

    sl = (sl == 2) ? 0 : sl + 1;
    slw = (slw == 2) ? 0 : slw + 1;
  }

  // Epilogue. C/D layout: col = lane&15, row = 4*(lane>>4)+j.
  const int crow = (l >> 4) * 4, ccol = l & 15;
  #pragma unroll
  for (int m = 0; m < 4; ++m) {
    const int rq = m0 + wr + m * 16 + crow;
    #pragma unroll
    for (int n = 0; n < 4; ++n) {
      const int c = n0 + wc + n * 16 + ccol;
      const float bv = BIAS ? bias[(size_t)z * biasB + c] : 0.0f;
      if (OUTM == 0) {
        float* C = (float*)Cv + (size_t)z * cB;
        #pragma unroll
        for (int j = 0; j < 4; j++)
          C[(size_t)(rq + j) * N + c] = acc[m][n][j] + bv;
      } else if (OUTM == 5 || OUTM == 6) {
        _Float16* C = (_Float16*)Cv + (size_t)z * cB;
        #pragma unroll
        for (int j = 0; j < 4; j++)
          C[(size_t)(rq + j) * N + c] = (_Float16)(acc[m][n][j] + bv);
      } else {
        _Float16* C = (_Float16*)Cv + (size_t)z * cB;
        const bool tr = (OUTM == 3) ? (z == 2) : (z < 2);
        if (tr) {
          const int bq = rq >> 10, s = rq & 1023;
          f16x4 o;
          #pragma unroll
          for (int j = 0; j < 4; j++) o[j] = (_Float16)(acc[m][n][j] + bv);
          *(f16x4*)&C[((size_t)(bq * N + c) << 10) + s] = o;
        } else {
          #pragma unroll
          for (int j = 0; j < 4; j++)
            C[(size_t)(rq + j) * N + c] = (_Float16)(acc[m][n][j] + bv);
        }
      }
    }
  }

  if (OUTM == 6) {
    // fused LN partial stats over this block's fp32 acc
    float ls = 0.0f, lq = 0.0f;
    #pragma unroll
    for (int m = 0; m < 4; ++m)
      #pragma unroll
      for (int n = 0; n < 4; ++n)
        #pragma unroll
        for (int j = 0; j < 4; j++) {
          const float v = acc[m][n][j];
          ls += v; lq += v * v;
        }
    __syncthreads();
    float* red = (float*)lds;
    red[t] = ls; red[512 + t] = lq;
    __syncthreads();
    #pragma unroll
    for (int off = 256; off > 0; off >>= 1) {
      if (t < off) { red[t] += red[t + off]; red[512 + t] += red[512 + t + off]; }
      __syncthreads();
    }
    if (t == 0) {
      const int chunk = blockIdx.x * 6 + blockIdx.y;   // 0..23
      aux[(z * 24 + chunk) * 2]     = red[0];
      aux[(z * 24 + chunk) * 2 + 1] = red[512];
    }
  }
}

// Fused tokens cast fp32->fp16 + token-pool partials
__global__ __launch_bounds__(256) void cast_pool(const float* __restrict__ tokens,
                                                 _Float16* __restrict__ tok_h,
                                                 float* __restrict__ tpart)
{
  const int b = blockIdx.y, ch = blockIdx.x, t = threadIdx.x;
  float s0 = 0, s1 = 0, s2 = 0;
  float x0 = -3.4e38f, x1 = -3.4e38f, x2 = -3.4e38f;
  const size_t rowbase = ((size_t)b * SS + ch * 32) * DD;
  for (int i = 0; i < 32; i++) {
    const float* tr = tokens + rowbase + (size_t)i * DD;
    _Float16* hw = tok_h + rowbase + (size_t)i * DD;
    float t0 = tr[t], t1 = tr[t + 256], t2 = tr[t + 512];
    hw[t] = (_Float16)t0; hw[t + 256] = (_Float16)t1; hw[t + 512] = (_Float16)t2;
    s0 += t0; s1 += t1; s2 += t2;
    x0 = fmaxf(x0, t0); x1 = fmaxf(x1, t1); x2 = fmaxf(x2, t2);
  }
  float* pb = tpart + (size_t)(b * 32 + ch) * 1536;
  pb[t] = s0;        pb[t + 256] = s1;        pb[t + 512] = s2;
  pb[768 + t] = x0;  pb[768 + t + 256] = x1;  pb[768 + t + 512] = x2;
}

// Batched fp32 [768][768] -> fp16 [768][768]^T for {Wk, Wq, Wv} (z selects)
__global__ __launch_bounds__(256) void transpose_w3(const float* __restrict__ Wk,
                                                    const float* __restrict__ Wq,
                                                    const float* __restrict__ Wv,
                                                    _Float16* __restrict__ outp)
{
  __shared__ float tile[32][33];
  const int zz = blockIdx.z;
  const float* in = (zz == 0) ? Wk : (zz == 1) ? Wq : Wv;
  _Float16* ob = outp + (size_t)zz * 589824;
  const int r0 = blockIdx.y * 32, c0 = blockIdx.x * 32;
  const int tx = threadIdx.x & 31, ty = threadIdx.x >> 5;  // 32 x 8
  #pragma unroll
  for (int i = 0; i < 4; i++)
    tile[ty + i * 8][tx] = in[(size_t)(r0 + ty + i * 8) * 768 + c0 + tx];
  __syncthreads();
  #pragma unroll
  for (int i = 0; i < 4; i++)
    ob[(size_t)(c0 + ty + i * 8) * 768 + r0 + tx] = (_Float16)tile[tx][ty + i * 8];
}

// fp16 [R][C] -> [C][R], batched over blockIdx.z
__global__ __launch_bounds__(256) void transpose_b2h(const _Float16* __restrict__ in, long long inB,
                                                     _Float16* __restrict__ outp, long long outB,
                                                     int R, int C)
{
  __shared__ _Float16 tile[32][33];
  const _Float16* ib = in + (size_t)blockIdx.z * inB;
  _Float16* ob = outp + (size_t)blockIdx.z * outB;
  const int r0 = blockIdx.y * 32, c0 = blockIdx.x * 32;
  const int tx = threadIdx.x & 31, ty = threadIdx.x >> 5;
  #pragma unroll
  for (int i = 0; i < 4; i++)
    tile[ty + i * 8][tx] = ib[(size_t)(r0 + ty + i * 8) * C + c0 + tx];
  __syncthreads();
  #pragma unroll
  for (int i = 0; i < 4; i++)
    ob[(size_t)(c0 + ty + i * 8) * R + r0 + tx] = tile[tx][ty + i * 8];
}

__global__ void pack_bias(const float* __restrict__ a, const float* __restrict__ b,
                          const float* __restrict__ c, float* __restrict__ o)
{
  int t = blockIdx.x * 256 + threadIdx.x;
  if (t < 768) o[t] = a[t];
  else if (t < 1536) o[t] = b[t - 768];
  else if (t < 2304) o[t] = c[t - 1536];
}

// Row softmax: fp16 in, fp16 out. L = VPT*256.
template<int VPT>
__global__ __launch_bounds__(256) void softmax_h2h(const _Float16* __restrict__ X,
                                                   _Float16* __restrict__ Y,
                                                   int L, float scale)
{
  const size_t base = (size_t)blockIdx.x * L;
  const int t = threadIdx.x;
  float v[VPT];
  float m = -3.4e38f;
  #pragma unroll
  for (int j = 0; j < VPT; j++) { v[j] = (float)X[base + t + j * 256]; m = fmaxf(m, v[j]); }
  __shared__ float red[256];
  red[t] = m; __syncthreads();
  #pragma unroll
  for (int off = 128; off > 0; off >>= 1) {
    if (t < off) red[t] = fmaxf(red[t], red[t + off]);
    __syncthreads();
  }
  m = red[0]; __syncthreads();
  float s = 0.0f;
  #pragma unroll
  for (int j = 0; j < VPT; j++) { v[j] = __expf((v[j] - m) * scale); s += v[j]; }
  red[t] = s; __syncthreads();
  #pragma unroll
  for (int off = 128; off > 0; off >>= 1) {
    if (t < off) red[t] += red[t + off];
    __syncthreads();
  }
  const float inv = 1.0f / red[0];
  #pragma unroll
  for (int j = 0; j < VPT; j++) Y[base + t + j * 256] = (_Float16)(v[j] * inv);
}

// Combine 24 LN partials per batch -> {mu, rsigma}
__global__ void ln_final(const float* __restrict__ part, float* __restrict__ stats)
{
  const int b = blockIdx.x, t = threadIdx.x;  // 64 threads = 1 wave
  float s = 0.0f, q = 0.0f;
  if (t < 24) { s = part[(b * 24 + t) * 2]; q = part[(b * 24 + t) * 2 + 1]; }
  #pragma unroll
  for (int off = 32; off > 0; off >>= 1) { s += __shfl_down(s, off); q += __shfl_down(q, off); }
  if (t == 0) {
    const float invN = 1.0f / (float)(SS * DD);
    float mu = s * invN;
    float var = q * invN - mu * mu;
    stats[b * 2] = mu;
    stats[b * 2 + 1] = rsqrtf(var + 1e-8f);
  }
}

// In-place LN apply on fp16 OUT
__global__ __launch_bounds__(256) void ln_apply_h(_Float16* __restrict__ data,
                                                  const float* __restrict__ g,
                                                  const float* __restrict__ bta,
                                                  const float* __restrict__ stats)
{
  const long long n4 = (long long)BB * SS * DD / 4;
  const int SD4 = SS * DD / 4;
  for (long long i = (long long)blockIdx.x * 256 + threadIdx.x; i < n4;
       i += (long long)gridDim.x * 256) {
    const int b = (int)(i / SD4);
    const int sd4 = (int)(i - (long long)b * SD4);
    const float mu = stats[b * 2], rs = stats[b * 2 + 1];
    f16x4 v = ((const f16x4*)data)[i];
    float4 gg = ((const float4*)g)[sd4];
    float4 bb = ((const float4*)bta)[sd4];
    f16x4 r;
    r[0] = (_Float16)(((float)v[0] - mu) * rs * gg.x + bb.x);
    r[1] = (_Float16)(((float)v[1] - mu) * rs * gg.y + bb.y);
    r[2] = (_Float16)(((float)v[2] - mu) * rs * gg.z + bb.z);
    r[3] = (_Float16)(((float)v[3] - mu) * rs * gg.w + bb.w);
    ((f16x4*)data)[i] = r;
  }
}

// Fused gate + gated pool partials. Grid (32 chunks, 16 batches), 4 waves.
// Wave wv handles rows [ch*32 + wv*8, +8). Per row: in-register dot with
// W_sgsa (shfl-reduce), broadcast, then gated sum/max accumulated per-lane
// (12 cols each). Wave-granular partials: opart[(b*32+ch)*4 + wv][1536].
__global__ __launch_bounds__(256) void gpool(const _Float16* __restrict__ outN,
                                             const float* __restrict__ wsg,
                                             const float* __restrict__ bsg,
                                             float* __restrict__ opart)
{
  const int b = blockIdx.y, ch = blockIdx.x;
  const int wv = threadIdx.x >> 6, l = threadIdx.x & 63;
  float wreg[12];
  #pragma unroll
  for (int i = 0; i < 12; i++) wreg[i] = wsg[l + i * 64];
  const float b0 = bsg[0];
  float sacc[12], xacc[12];
  #pragma unroll
  for (int i = 0; i < 12; i++) { sacc[i] = 0.0f; xacc[i] = -3.4e38f; }
  const size_t rowbase = ((size_t)b * SS + ch * 32 + wv * 8) * DD;
  for (int r = 0; r < 8; r++) {
    const _Float16* row = outN + rowbase + (size_t)r * DD;
    float v[12];
    float dot = 0.0f;
    #pragma unroll
    for (int i = 0; i < 12; i++) { v[i] = (float)row[l + i * 64]; dot += v[i] * wreg[i]; }
    #pragma unroll
    for (int off = 32; off > 0; off >>= 1) dot += __shfl_down(dot, off);
    const float g = __shfl(dot, 0) + b0;
    #pragma unroll
    for (int i = 0; i < 12; i++) {
      const float o = v[i] * g;
      sacc[i] += o;
      xacc[i] = fmaxf(xacc[i], o);
    }
  }
  float* pb = opart + (size_t)(((b * 32 + ch) << 2) + wv) * 1536;
  #pragma unroll
  for (int i = 0; i < 12; i++) {
    pb[l + i * 64] = sacc[i];
    pb[768 + l + i * 64] = xacc[i];
  }
}

// Combine 32 token chunks + 128 gated-outN chunks -> pooled [B][4*768]
__global__ __launch_bounds__(256) void pool_final(const float* __restrict__ tpart,
                                                  const float* __restrict__ opart,
                                                  float* __restrict__ pooled)
{
  const int idx = blockIdx.x * 256 + threadIdx.x;  // < B*D
  const int b = idx / DD, d = idx - b * DD;
  float st = 0, xt = -3.4e38f;
  for (int ch = 0; ch < 32; ch++) {
    const float* tb = tpart + (size_t)(b * 32 + ch) * 1536;
    st += tb[d]; xt = fmaxf(xt, tb[768 + d]);
  }
  float so = 0, xo = -3.4e38f;
  for (int cj = 0; cj < 128; cj++) {
    const float* ob = opart + (size_t)(b * 128 + cj) * 1536;
    so += ob[d]; xo = fmaxf(xo, ob[768 + d]);
  }
  const float inv = 1.0f / (float)SS;
  pooled[(size_t)b * 3072 + d]        = st * inv;
  pooled[(size_t)b * 3072 + 768 + d]  = so * inv;
  pooled[(size_t)b * 3072 + 1536 + d] = xt;
  pooled[(size_t)b * 3072 + 2304 + d] = xo;
}

__global__ __launch_bounds__(256) void fc_k(const float* __restrict__ pooled,
                                            const float* __restrict__ Wf,
                                            const float* __restrict__ bf,
                                            float* __restrict__ outp)
{
  const int b = blockIdx.x, t = threadIdx.x;
  float p0 = 0.0f, p1 = 0.0f;
  #pragma unroll
  for (int i = 0; i < 12; i++) {
    const int j = t + i * 256;
    const float pv = pooled[(size_t)b * 3072 + j];
    p0 += pv * Wf[j * 2];
    p1 += pv * Wf[j * 2 + 1];
  }
  __shared__ float r0[256], r1[256];
  r0[t] = p0; r1[t] = p1; __syncthreads();
  #pragma unroll
  for (int off = 128; off > 0; off >>= 1) {
    if (t < off) { r0[t] += r0[t + off]; r1[t] += r1[t + off]; }
    __syncthreads();
  }
  if (t == 0) {
    outp[b * 2 + 0] = r0[0] + bf[0];
    outp[b * 2 + 1] = r1[0] + bf[1];
  }
}

// ---------------------------------------------------------------------------
// Host orchestration. fp16 everywhere except LN stats / pool partials.
// Region map (byte offsets), peak ~221 MB:
//   R0 @ 0         (33.6MB f16): scores -> attN_sc
//   R1 @ 67108864  (25.2MB f16): tokens_h -> OUT_h -> out_ln_h -> attNT_h
//   R2 @ 92274688  (25.2MB f16): K_h -> KtN_h
//   R3 @ 117440512 (25.2MB f16): Q_h -> QtN_h
//   R4 @ 142606336 (25.2MB f16): Vt_h -> VN_h
//   R5 @ 167772160 (33.6MB f16): att_h -> attN_h -> outN_h
//   Wt @ 201326592 (3.5MB f16)
// ---------------------------------------------------------------------------
extern "C" void kernel_launch(void* const* d_in, const int* in_sizes, int n_in,
                              void* d_out, int out_size, void* d_ws, size_t ws_size,
                              hipStream_t stream)
{
  const float* tokens = (const float*)d_in[0];
  const float* Wk  = (const float*)d_in[1];
  const float* bk  = (const float*)d_in[2];
  const float* Wq  = (const float*)d_in[3];
  const float* bq  = (const float*)d_in[4];
  const float* Wv  = (const float*)d_in[5];
  const float* bv  = (const float*)d_in[6];
  const float* lng = (const float*)d_in[7];
  const float* lnb = (const float*)d_in[8];
  const float* Wsg = (const float*)d_in[9];
  const float* bsg = (const float*)d_in[10];
  const float* Wf  = (const float*)d_in[11];
  const float* bfn = (const float*)d_in[12];
  float* outp = (float*)d_out;
  (void)in_sizes; (void)n_in; (void)out_size; (void)ws_size;

  char* ws = (char*)d_ws;
  _Float16* R0   = (_Float16*)(ws + 0);
  _Float16* R1   = (_Float16*)(ws + 67108864);
  _Float16* R2   = (_Float16*)(ws + 92274688);
  _Float16* R3   = (_Float16*)(ws + 117440512);
  _Float16* R4   = (_Float16*)(ws + 142606336);
  _Float16* R5   = (_Float16*)(ws + 167772160);
  _Float16* Wt   = (_Float16*)(ws + 201326592);   // 3,538,944 B
  float* bias3   = (float*)(ws + 204865536);      // 9,216 B
  float* lnpart  = (float*)(ws + 204874752);      // 3,072 B
  float* stats   = (float*)(ws + 204878848);      // 128 B
  float* tpart   = (float*)(ws + 204882944);      // 3,145,728 B
  float* opart   = (float*)(ws + 208028672);      // 12,582,912 B
  float* pooled  = (float*)(ws + 220611584);      // 196,608 B (end ~220.8MB)

  const float fact = 0.036084391824351615f;  // 1/sqrt(768)
  const long long SD = (long long)SS * DD;   // 786432
  const long long S2 = (long long)SS * SS;   // 1048576
  const long long D2 = (long long)DD * DD;   // 589824
  const long long PL = (long long)BB * SD;   // 12582912 (one K/Q/V plane)

  // 1. fused tokens cast + token-pool partials; weight prep (batched)
  cast_pool<<<dim3(32, BB), 256, 0, stream>>>(tokens, R1, tpart);
  transpose_w3<<<dim3(24, 24, 3), 256, 0, stream>>>(Wk, Wq, Wv, Wt);
  pack_bias<<<9, 256, 0, stream>>>(bk, bq, bv, bias3);

  // 2. Stage-1 projections: z0=K (R2), z1=Q (R3), z2=Vt (R4, transposed)
  gemm256<3, 1><<<dim3(18, 64), 512, 0, stream>>>(R1, 0, Wt, 589824, bias3, 768,
                                                  (void*)R2, PL, nullptr, BB * SS, DD, DD);
  // 3. scores = Q.K^T -> R0 fp16 [B,S,S]
  gemm256<5, 0><<<dim3(4, 8, 16), 512, 0, stream>>>(R3, SD, R2, SD, nullptr, 0,
                                                    (void*)R0, S2, nullptr, SS, SS, DD);
  // 4. att_h = softmax(scores*fact) -> R5 fp16
  softmax_h2h<4><<<BB * SS, 256, 0, stream>>>(R0, R5, SS, fact);
  // 5. OUT_h = att @ V -> R1 fp16 (tokens_h dead) + fused LN partials
  gemm256<6, 0><<<dim3(4, 6, 16), 512, 0, stream>>>(R5, S2, R4, SD, nullptr, 0,
                                                    (void*)R1, SD, lnpart, SS, DD, SS);
  // 6. LN: combine partials, apply in-place on R1 (fp16)
  ln_final<<<16, 64, 0, stream>>>(lnpart, stats);
  ln_apply_h<<<2048, 256, 0, stream>>>(R1, lng, lnb, stats);

  // 7. Stage-2 projections: z0=KtN (R2, tr), z1=QtN (R3, tr), z2=VN (R4)
  gemm256<4, 1><<<dim3(18, 64), 512, 0, stream>>>(R1, 0, Wt, 589824, bias3, 768,
                                                  (void*)R2, PL, nullptr, BB * SS, DD, DD);
  // 8. attN_sc = QtN .NT. KtN -> R0 fp16 [B,D,D]
  gemm256<5, 0><<<dim3(3, 6, 16), 512, 0, stream>>>(R3, SD, R2, SD, nullptr, 0,
                                                    (void*)R0, D2, nullptr, DD, DD, SS);
  // 9. attN_h = softmax -> R5 fp16
  softmax_h2h<3><<<BB * DD, 256, 0, stream>>>(R0, R5, DD, fact);
  // 10. attNT_h -> R1 (out_ln dead)
  transpose_b2h<<<dim3(24, 24, 16), 256, 0, stream>>>(R5, D2, R1, D2, DD, DD);
  // 11. outN_h = VN .NT. attNT -> R5 fp16 (attN dead)
  gemm256<5, 0><<<dim3(4, 6, 16), 512, 0, stream>>>(R4, SD, R1, D2, nullptr, 0,
                                                    (void*)R5, SD, nullptr, SS, DD, DD);

  // 12. fused gate+pool, combine, FC
  gpool<<<dim3(32, BB), 256, 0, stream>>>(R5, Wsg, bsg, opart);
  pool_final<<<48, 256, 0, stream>>>(tpart, opart, pooled);
  fc_k<<<16, 256, 0, stream>>>(pooled, Wf, bfn, outp);
}

// Round 18
// 401.186 us; speedup vs baseline: 1.0165x; 1.0165x over previous
//
#include <hip/hip_runtime.h>

// Problem constants
#define BB 16
#define SS 1024
#define DD 768

typedef _Float16 f16x4 __attribute__((ext_vector_type(4)));
typedef _Float16 f16x8 __attribute__((ext_vector_type(8)));
typedef float f32x4 __attribute__((ext_vector_type(4)));

__device__ __forceinline__ void gload_lds16(const void* g, void* l) {
  __builtin_amdgcn_global_load_lds(
      (const __attribute__((address_space(1))) unsigned int*)g,
      (__attribute__((address_space(3))) unsigned int*)l, 16, 0, 0);
}

// ---------------------------------------------------------------------------
// 256x128 NT GEMM: 2-blocks/CU, zero-conflict LDS (verified r14), ring-3
// slots + counted vmcnt(3) (verified r15/r16: 92->82us, MfmaUtil 26->30%).
// Round-17 lesson: gpool fusion regressed (wave-granular partials 4x the
// combine traffic + serialized per-row shfl chains); this round reverts to
// the measured-best round-16 configuration exactly.
//
// LDS: 3 slots x (A 16KB + B 8KB) = 72 KiB -> still 2 blocks/CU.
// Slab layout (empirically zero-conflict): 128B pairs, element (row R,
// chunk c) at pair P=R>>1, slot q=((R&1)<<2)|(c^(P&3)).
// Staging inverse: thread t -> P=t>>3,q=t&7: src row 2P+(q>>2), chunk
// (q&3)^(P&3); dest linear t*16. Wave covers 16 full 64B segs (coalesced).
//
// Schedule per tile T: vmcnt(3) [retires T's 3 loads; T+1's stay in
// flight; vmcnt(0) only at T==NT-1]; barrier; stage T+2 -> slot (T+2)%3
// (WAR-safe: that slot's readers were tile T-1, their ds_reads retired
// before their MFMAs hence before this barrier); 8 ds_read_b128; 16 MFMA.
//
// OUTM: 0 fp32 row-major |
//       3 f16 z<2 row-major / z==2 transposed (stage-1 projections) |
//       4 f16 z<2 transposed / z==2 row-major (stage-2 projections) |
//       5 f16 row-major | 6 f16 row-major + LN partials aux[(z*24+bx*6+by)*2]
// Transposed = per-1024-row batch: C[z][(b*N+c)*1024 + s], b=row>>10.
// OUTM 3/4: grid (18,64), XCD-grouped decode (round-7 lesson).
// ---------------------------------------------------------------------------
template<int OUTM, int BIAS>
__global__ __launch_bounds__(512, 4) void gemm256(
    const _Float16* __restrict__ A, long long aB,
    const _Float16* __restrict__ Bt, long long bB,
    const float* __restrict__ bias, int biasB,
    void* __restrict__ Cv, long long cB,
    float* __restrict__ aux,
    int M, int N, int K)
{
  __shared__ __attribute__((aligned(16))) _Float16 lds[36864];  // 72 KiB
  const int t = threadIdx.x;
  int z, m0, n0;
  if (OUTM == 3 || OUTM == 4) {     // projection decode, XCD-grouped
    const int lin = blockIdx.x + 18 * blockIdx.y;  // 0..1151
    const int xcd = lin & 7, idx = lin >> 3;       // idx 0..143
    const int mt  = xcd * 8 + idx / 18;
    const int zn  = idx % 18;
    z  = zn / 6;
    n0 = (zn % 6) * 128;
    m0 = mt * 256;
  } else {
    z = blockIdx.z;
    m0 = blockIdx.x * 256;
    n0 = blockIdx.y * 128;
  }
  const _Float16* Ab = A + (size_t)z * aB;
  const _Float16* Bb = Bt + (size_t)z * bB;

  const int l = t & 63, w = t >> 6;
  const int wr = (w >> 1) * 64, wc = (w & 1) * 64;
  const int lrow = l & 15, kq = l >> 4;
  // read-side: pair-interleaved involution (measured 0 conflicts)
  const int qread = ((lrow & 1) << 2) | (kq ^ ((lrow >> 1) & 3));
  const int fragoff = (lrow >> 1) * 128 + qread * 16;

  // staging lane constants (inverse of the same involution)
  const int sp = t >> 3, sq = t & 7;
  const int srow = 2 * sp + (sq >> 2);
  const int schk = (sq & 3) ^ (sp & 3);
  const size_t ldK = (size_t)K * 2;
  const char* pA0 = (const char*)Ab + (size_t)(m0 + srow) * ldK + schk * 16;
  const char* pA1 = pA0 + (size_t)128 * ldK;
  const char* pB0 = (const char*)Bb + (size_t)(n0 + srow) * ldK + schk * 16;
  char* const ldsb = (char*)lds;
  const int dstt = t * 16;

  // stage K-tile T into ring slot sl: A (2 gloads) + B (1 gload)
  auto stg = [&](int T, int sl) {
    const char* ga0 = pA0 + (size_t)T * 64;
    const char* ga1 = pA1 + (size_t)T * 64;
    const char* gb  = pB0 + (size_t)T * 64;
    char* d = ldsb + sl * 24576 + dstt;
    gload_lds16(ga0, d);
    gload_lds16(ga1, d + 8192);
    gload_lds16(gb,  d + 16384);
  };

  f32x4 acc[4][4] = {};
  f16x8 af[4], bf[4];

  // prologue: tiles 0,1 -> slots 0,1
  stg(0, 0);
  stg(1, 1);

  const int NT = K >> 5;
  int sl = 0, slw = 2;   // read slot of T; write slot of T+2
  for (int T = 0; T < NT; ++T) {
    const char* Abase = ldsb + sl * 24576;
    const char* Bbase = Abase + 16384;

    if (T == NT - 1) asm volatile("s_waitcnt vmcnt(0)" ::: "memory");
    else             asm volatile("s_waitcnt vmcnt(3)" ::: "memory");
    __builtin_amdgcn_s_barrier();
    asm volatile("" ::: "memory");
    if (T + 2 < NT) stg(T + 2, slw);

    #pragma unroll
    for (int n = 0; n < 4; n++)
      bf[n] = *(const f16x8*)(Bbase + (wc + n * 16) * 64 + fragoff);
    #pragma unroll
    for (int mi = 0; mi < 4; mi++)
      af[mi] = *(const f16x8*)(Abase + (wr + mi * 16) * 64 + fragoff);

    __builtin_amdgcn_s_setprio(1);
    #pragma unroll
    for (int mi = 0; mi < 4; mi++)
      #pragma unroll
      for (int n = 0; n < 4; n++)
        acc[mi][n] = __builtin_amdgcn_mfma_f32_16x16x32_f16(af[mi], bf[n], acc[mi][n], 0, 0, 0);
    __builtin_amdgcn_s_setprio(0);

    sl = (sl == 2) ? 0 : sl + 1;
    slw = (slw == 2) ? 0 : slw + 1;
  }

  // Epilogue. C/D layout: col = lane&15, row = 4*(lane>>4)+j.
  const int crow = (l >> 4) * 4, ccol = l & 15;
  #pragma unroll
  for (int m = 0; m < 4; ++m) {
    const int rq = m0 + wr + m * 16 + crow;
    #pragma unroll
    for (int n = 0; n < 4; ++n) {
      const int c = n0 + wc + n * 16 + ccol;
      const float bv = BIAS ? bias[(size_t)z * biasB + c] : 0.0f;
      if (OUTM == 0) {
        float* C = (float*)Cv + (size_t)z * cB;
        #pragma unroll
        for (int j = 0; j < 4; j++)
          C[(size_t)(rq + j) * N + c] = acc[m][n][j] + bv;
      } else if (OUTM == 5 || OUTM == 6) {
        _Float16* C = (_Float16*)Cv + (size_t)z * cB;
        #pragma unroll
        for (int j = 0; j < 4; j++)
          C[(size_t)(rq + j) * N + c] = (_Float16)(acc[m][n][j] + bv);
      } else {
        _Float16* C = (_Float16*)Cv + (size_t)z * cB;
        const bool tr = (OUTM == 3) ? (z == 2) : (z < 2);
        if (tr) {
          const int bq = rq >> 10, s = rq & 1023;
          f16x4 o;
          #pragma unroll
          for (int j = 0; j < 4; j++) o[j] = (_Float16)(acc[m][n][j] + bv);
          *(f16x4*)&C[((size_t)(bq * N + c) << 10) + s] = o;
        } else {
          #pragma unroll
          for (int j = 0; j < 4; j++)
            C[(size_t)(rq + j) * N + c] = (_Float16)(acc[m][n][j] + bv);
        }
      }
    }
  }

  if (OUTM == 6) {
    // fused LN partial stats over this block's fp32 acc
    float ls = 0.0f, lq = 0.0f;
    #pragma unroll
    for (int m = 0; m < 4; ++m)
      #pragma unroll
      for (int n = 0; n < 4; ++n)
        #pragma unroll
        for (int j = 0; j < 4; j++) {
          const float v = acc[m][n][j];
          ls += v; lq += v * v;
        }
    __syncthreads();
    float* red = (float*)lds;
    red[t] = ls; red[512 + t] = lq;
    __syncthreads();
    #pragma unroll
    for (int off = 256; off > 0; off >>= 1) {
      if (t < off) { red[t] += red[t + off]; red[512 + t] += red[512 + t + off]; }
      __syncthreads();
    }
    if (t == 0) {
      const int chunk = blockIdx.x * 6 + blockIdx.y;   // 0..23
      aux[(z * 24 + chunk) * 2]     = red[0];
      aux[(z * 24 + chunk) * 2 + 1] = red[512];
    }
  }
}

// Fused tokens cast fp32->fp16 + token-pool partials
__global__ __launch_bounds__(256) void cast_pool(const float* __restrict__ tokens,
                                                 _Float16* __restrict__ tok_h,
                                                 float* __restrict__ tpart)
{
  const int b = blockIdx.y, ch = blockIdx.x, t = threadIdx.x;
  float s0 = 0, s1 = 0, s2 = 0;
  float x0 = -3.4e38f, x1 = -3.4e38f, x2 = -3.4e38f;
  const size_t rowbase = ((size_t)b * SS + ch * 32) * DD;
  for (int i = 0; i < 32; i++) {
    const float* tr = tokens + rowbase + (size_t)i * DD;
    _Float16* hw = tok_h + rowbase + (size_t)i * DD;
    float t0 = tr[t], t1 = tr[t + 256], t2 = tr[t + 512];
    hw[t] = (_Float16)t0; hw[t + 256] = (_Float16)t1; hw[t + 512] = (_Float16)t2;
    s0 += t0; s1 += t1; s2 += t2;
    x0 = fmaxf(x0, t0); x1 = fmaxf(x1, t1); x2 = fmaxf(x2, t2);
  }
  float* pb = tpart + (size_t)(b * 32 + ch) * 1536;
  pb[t] = s0;        pb[t + 256] = s1;        pb[t + 512] = s2;
  pb[768 + t] = x0;  pb[768 + t + 256] = x1;  pb[768 + t + 512] = x2;
}

// fp32 [R][C] -> fp16 [C][R] (weights transpose+cast)
__global__ __launch_bounds__(256) void transpose_f2h(const float* __restrict__ in,
                                                     _Float16* __restrict__ outp, int R, int C)
{
  __shared__ float tile[32][33];
  const int r0 = blockIdx.y * 32, c0 = blockIdx.x * 32;
  const int tx = threadIdx.x & 31, ty = threadIdx.x >> 5;  // 32 x 8
  #pragma unroll
  for (int i = 0; i < 4; i++)
    tile[ty + i * 8][tx] = in[(size_t)(r0 + ty + i * 8) * C + c0 + tx];
  __syncthreads();
  #pragma unroll
  for (int i = 0; i < 4; i++)
    outp[(size_t)(c0 + ty + i * 8) * R + r0 + tx] = (_Float16)tile[tx][ty + i * 8];
}

// fp16 [R][C] -> [C][R], batched over blockIdx.z
__global__ __launch_bounds__(256) void transpose_b2h(const _Float16* __restrict__ in, long long inB,
                                                     _Float16* __restrict__ outp, long long outB,
                                                     int R, int C)
{
  __shared__ _Float16 tile[32][33];
  const _Float16* ib = in + (size_t)blockIdx.z * inB;
  _Float16* ob = outp + (size_t)blockIdx.z * outB;
  const int r0 = blockIdx.y * 32, c0 = blockIdx.x * 32;
  const int tx = threadIdx.x & 31, ty = threadIdx.x >> 5;
  #pragma unroll
  for (int i = 0; i < 4; i++)
    tile[ty + i * 8][tx] = ib[(size_t)(r0 + ty + i * 8) * C + c0 + tx];
  __syncthreads();
  #pragma unroll
  for (int i = 0; i < 4; i++)
    ob[(size_t)(c0 + ty + i * 8) * R + r0 + tx] = tile[tx][ty + i * 8];
}

__global__ void pack_bias(const float* __restrict__ a, const float* __restrict__ b,
                          const float* __restrict__ c, float* __restrict__ o)
{
  int t = blockIdx.x * 256 + threadIdx.x;
  if (t < 768) o[t] = a[t];
  else if (t < 1536) o[t] = b[t - 768];
  else if (t < 2304) o[t] = c[t - 1536];
}

// Row softmax: fp16 in, fp16 out. L = VPT*256.
template<int VPT>
__global__ __launch_bounds__(256) void softmax_h2h(const _Float16* __restrict__ X,
                                                   _Float16* __restrict__ Y,
                                                   int L, float scale)
{
  const size_t base = (size_t)blockIdx.x * L;
  const int t = threadIdx.x;
  float v[VPT];
  float m = -3.4e38f;
  #pragma unroll
  for (int j = 0; j < VPT; j++) { v[j] = (float)X[base + t + j * 256]; m = fmaxf(m, v[j]); }
  __shared__ float red[256];
  red[t] = m; __syncthreads();
  #pragma unroll
  for (int off = 128; off > 0; off >>= 1) {
    if (t < off) red[t] = fmaxf(red[t], red[t + off]);
    __syncthreads();
  }
  m = red[0]; __syncthreads();
  float s = 0.0f;
  #pragma unroll
  for (int j = 0; j < VPT; j++) { v[j] = __expf((v[j] - m) * scale); s += v[j]; }
  red[t] = s; __syncthreads();
  #pragma unroll
  for (int off = 128; off > 0; off >>= 1) {
    if (t < off) red[t] += red[t + off];
    __syncthreads();
  }
  const float inv = 1.0f / red[0];
  #pragma unroll
  for (int j = 0; j < VPT; j++) Y[base + t + j * 256] = (_Float16)(v[j] * inv);
}

// Combine 24 LN partials per batch -> {mu, rsigma}
__global__ void ln_final(const float* __restrict__ part, float* __restrict__ stats)
{
  const int b = blockIdx.x, t = threadIdx.x;  // 64 threads = 1 wave
  float s = 0.0f, q = 0.0f;
  if (t < 24) { s = part[(b * 24 + t) * 2]; q = part[(b * 24 + t) * 2 + 1]; }
  #pragma unroll
  for (int off = 32; off > 0; off >>= 1) { s += __shfl_down(s, off); q += __shfl_down(q, off); }
  if (t == 0) {
    const float invN = 1.0f / (float)(SS * DD);
    float mu = s * invN;
    float var = q * invN - mu * mu;
    stats[b * 2] = mu;
    stats[b * 2 + 1] = rsqrtf(var + 1e-8f);
  }
}

// In-place LN apply on fp16 OUT
__global__ __launch_bounds__(256) void ln_apply_h(_Float16* __restrict__ data,
                                                  const float* __restrict__ g,
                                                  const float* __restrict__ bta,
                                                  const float* __restrict__ stats)
{
  const long long n4 = (long long)BB * SS * DD / 4;
  const int SD4 = SS * DD / 4;
  for (long long i = (long long)blockIdx.x * 256 + threadIdx.x; i < n4;
       i += (long long)gridDim.x * 256) {
    const int b = (int)(i / SD4);
    const int sd4 = (int)(i - (long long)b * SD4);
    const float mu = stats[b * 2], rs = stats[b * 2 + 1];
    f16x4 v = ((const f16x4*)data)[i];
    float4 gg = ((const float4*)g)[sd4];
    float4 bb = ((const float4*)bta)[sd4];
    f16x4 r;
    r[0] = (_Float16)(((float)v[0] - mu) * rs * gg.x + bb.x);
    r[1] = (_Float16)(((float)v[1] - mu) * rs * gg.y + bb.y);
    r[2] = (_Float16)(((float)v[2] - mu) * rs * gg.z + bb.z);
    r[3] = (_Float16)(((float)v[3] - mu) * rs * gg.w + bb.w);
    ((f16x4*)data)[i] = r;
  }
}

// gate[b,s] = dot(src[b,s,:], w) + b0[0] ; one wave per row; fp16 src
__global__ __launch_bounds__(256) void gate_k(const _Float16* __restrict__ src,
                                              const float* __restrict__ wv,
                                              const float* __restrict__ b0,
                                              float* __restrict__ outv)
{
  const int row = blockIdx.x * 4 + (threadIdx.x >> 6);
  const int l = threadIdx.x & 63;
  const _Float16* s0 = src + (size_t)row * DD;
  float s = 0.0f;
  #pragma unroll
  for (int i = 0; i < 12; i++) s += (float)s0[l + i * 64] * wv[l + i * 64];
  #pragma unroll
  for (int off = 32; off > 0; off >>= 1) s += __shfl_down(s, off);
  if (l == 0) outv[row] = s + b0[0];
}

// Gated-outN pool partials: grid (32,16); 32 rows x 768 cols per block
__global__ __launch_bounds__(256) void opool(const _Float16* __restrict__ outN,
                                             const float* __restrict__ gate,
                                             float* __restrict__ opart)
{
  const int b = blockIdx.y, ch = blockIdx.x, t = threadIdx.x;
  float s0 = 0, s1 = 0, s2 = 0;
  float x0 = -3.4e38f, x1 = -3.4e38f, x2 = -3.4e38f;
  const size_t rowbase = ((size_t)b * SS + ch * 32) * DD;
  for (int i = 0; i < 32; i++) {
    const _Float16* orw = outN + rowbase + (size_t)i * DD;
    const float g = gate[b * SS + ch * 32 + i];
    float o0 = (float)orw[t] * g, o1 = (float)orw[t + 256] * g, o2 = (float)orw[t + 512] * g;
    s0 += o0; s1 += o1; s2 += o2;
    x0 = fmaxf(x0, o0); x1 = fmaxf(x1, o1); x2 = fmaxf(x2, o2);
  }
  float* pb = opart + (size_t)(b * 32 + ch) * 1536;
  pb[t] = s0;        pb[t + 256] = s1;        pb[t + 512] = s2;
  pb[768 + t] = x0;  pb[768 + t + 256] = x1;  pb[768 + t + 512] = x2;
}

// Combine 32 chunks of token + gated-outN partials -> pooled [B][4*768]
__global__ __launch_bounds__(256) void pool_final(const float* __restrict__ tpart,
                                                  const float* __restrict__ opart,
                                                  float* __restrict__ pooled)
{
  const int idx = blockIdx.x * 256 + threadIdx.x;  // < B*D
  const int b = idx / DD, d = idx - b * DD;
  float st = 0, so = 0, xt = -3.4e38f, xo = -3.4e38f;
  for (int ch = 0; ch < 32; ch++) {
    const float* tb = tpart + (size_t)(b * 32 + ch) * 1536;
    const float* ob = opart + (size_t)(b * 32 + ch) * 1536;
    st += tb[d]; xt = fmaxf(xt, tb[768 + d]);
    so += ob[d]; xo = fmaxf(xo, ob[768 + d]);
  }
  const float inv = 1.0f / (float)SS;
  pooled[(size_t)b * 3072 + d]        = st * inv;
  pooled[(size_t)b * 3072 + 768 + d]  = so * inv;
  pooled[(size_t)b * 3072 + 1536 + d] = xt;
  pooled[(size_t)b * 3072 + 2304 + d] = xo;
}

__global__ __launch_bounds__(256) void fc_k(const float* __restrict__ pooled,
                                            const float* __restrict__ Wf,
                                            const float* __restrict__ bf,
                                            float* __restrict__ outp)
{
  const int b = blockIdx.x, t = threadIdx.x;
  float p0 = 0.0f, p1 = 0.0f;
  #pragma unroll
  for (int i = 0; i < 12; i++) {
    const int j = t + i * 256;
    const float pv = pooled[(size_t)b * 3072 + j];
    p0 += pv * Wf[j * 2];
    p1 += pv * Wf[j * 2 + 1];
  }
  __shared__ float r0[256], r1[256];
  r0[t] = p0; r1[t] = p1; __syncthreads();
  #pragma unroll
  for (int off = 128; off > 0; off >>= 1) {
    if (t < off) { r0[t] += r0[t + off]; r1[t] += r1[t + off]; }
    __syncthreads();
  }
  if (t == 0) {
    outp[b * 2 + 0] = r0[0] + bf[0];
    outp[b * 2 + 1] = r1[0] + bf[1];
  }
}

// ---------------------------------------------------------------------------
// Host orchestration (round-16 measured-best pipeline). fp16 everywhere
// except LN stats / pool partials. Region map (byte offsets), peak ~202 MB:
//   R0 @ 0         (33.6MB f16): scores -> attN_sc
//   R1 @ 67108864  (25.2MB f16): tokens_h -> OUT_h -> out_ln_h -> attNT_h
//   R2 @ 92274688  (25.2MB f16): K_h -> KtN_h
//   R3 @ 117440512 (25.2MB f16): Q_h -> QtN_h
//   R4 @ 142606336 (25.2MB f16): Vt_h -> VN_h
//   R5 @ 167772160 (33.6MB f16): att_h -> attN_h -> outN_h
//   Wt @ 201326592 (3.5MB f16)
// ---------------------------------------------------------------------------
extern "C" void kernel_launch(void* const* d_in, const int* in_sizes, int n_in,
                              void* d_out, int out_size, void* d_ws, size_t ws_size,
                              hipStream_t stream)
{
  const float* tokens = (const float*)d_in[0];
  const float* Wk  = (const float*)d_in[1];
  const float* bk  = (const float*)d_in[2];
  const float* Wq  = (const float*)d_in[3];
  const float* bq  = (const float*)d_in[4];
  const float* Wv  = (const float*)d_in[5];
  const float* bv  = (const float*)d_in[6];
  const float* lng = (const float*)d_in[7];
  const float* lnb = (const float*)d_in[8];
  const float* Wsg = (const float*)d_in[9];
  const float* bsg = (const float*)d_in[10];
  const float* Wf  = (const float*)d_in[11];
  const float* bfn = (const float*)d_in[12];
  float* outp = (float*)d_out;
  (void)in_sizes; (void)n_in; (void)out_size; (void)ws_size;

  char* ws = (char*)d_ws;
  _Float16* R0   = (_Float16*)(ws + 0);
  _Float16* R1   = (_Float16*)(ws + 67108864);
  _Float16* R2   = (_Float16*)(ws + 92274688);
  _Float16* R3   = (_Float16*)(ws + 117440512);
  _Float16* R4   = (_Float16*)(ws + 142606336);
  _Float16* R5   = (_Float16*)(ws + 167772160);
  _Float16* Wt   = (_Float16*)(ws + 201326592);   // 3,538,944 B
  float* bias3   = (float*)(ws + 204865536);      // 9,216 B
  float* lnpart  = (float*)(ws + 204874752);      // 3,072 B
  float* stats   = (float*)(ws + 204878848);      // 128 B
  float* gate    = (float*)(ws + 204878976);      // 65,536 B
  float* tpart   = (float*)(ws + 204944512);      // 3,145,728 B
  float* opart   = (float*)(ws + 208090240);      // 3,145,728 B
  float* pooled  = (float*)(ws + 211235968);      // 196,608 B (end ~201.7MB)

  const float fact = 0.036084391824351615f;  // 1/sqrt(768)
  const long long SD = (long long)SS * DD;   // 786432
  const long long S2 = (long long)SS * SS;   // 1048576
  const long long D2 = (long long)DD * DD;   // 589824
  const long long PL = (long long)BB * SD;   // 12582912 (one K/Q/V plane)

  // 1. fused tokens cast + token-pool partials; weight prep
  cast_pool<<<dim3(32, BB), 256, 0, stream>>>(tokens, R1, tpart);
  transpose_f2h<<<dim3(24, 24), 256, 0, stream>>>(Wk, Wt,               768, 768);
  transpose_f2h<<<dim3(24, 24), 256, 0, stream>>>(Wq, Wt + 589824,      768, 768);
  transpose_f2h<<<dim3(24, 24), 256, 0, stream>>>(Wv, Wt + 2 * 589824,  768, 768);
  pack_bias<<<9, 256, 0, stream>>>(bk, bq, bv, bias3);

  // 2. Stage-1 projections: z0=K (R2), z1=Q (R3), z2=Vt (R4, transposed)
  gemm256<3, 1><<<dim3(18, 64), 512, 0, stream>>>(R1, 0, Wt, 589824, bias3, 768,
                                                  (void*)R2, PL, nullptr, BB * SS, DD, DD);
  // 3. scores = Q.K^T -> R0 fp16 [B,S,S]
  gemm256<5, 0><<<dim3(4, 8, 16), 512, 0, stream>>>(R3, SD, R2, SD, nullptr, 0,
                                                    (void*)R0, S2, nullptr, SS, SS, DD);
  // 4. att_h = softmax(scores*fact) -> R5 fp16
  softmax_h2h<4><<<BB * SS, 256, 0, stream>>>(R0, R5, SS, fact);
  // 5. OUT_h = att @ V -> R1 fp16 (tokens_h dead) + fused LN partials
  gemm256<6, 0><<<dim3(4, 6, 16), 512, 0, stream>>>(R5, S2, R4, SD, nullptr, 0,
                                                    (void*)R1, SD, lnpart, SS, DD, SS);
  // 6. LN: combine partials, apply in-place on R1 (fp16)
  ln_final<<<16, 64, 0, stream>>>(lnpart, stats);
  ln_apply_h<<<2048, 256, 0, stream>>>(R1, lng, lnb, stats);

  // 7. Stage-2 projections: z0=KtN (R2, tr), z1=QtN (R3, tr), z2=VN (R4)
  gemm256<4, 1><<<dim3(18, 64), 512, 0, stream>>>(R1, 0, Wt, 589824, bias3, 768,
                                                  (void*)R2, PL, nullptr, BB * SS, DD, DD);
  // 8. attN_sc = QtN .NT. KtN -> R0 fp16 [B,D,D]
  gemm256<5, 0><<<dim3(3, 6, 16), 512, 0, stream>>>(R3, SD, R2, SD, nullptr, 0,
                                                    (void*)R0, D2, nullptr, DD, DD, SS);
  // 9. attN_h = softmax -> R5 fp16
  softmax_h2h<3><<<BB * DD, 256, 0, stream>>>(R0, R5, DD, fact);
  // 10. attNT_h -> R1 (out_ln dead)
  transpose_b2h<<<dim3(24, 24, 16), 256, 0, stream>>>(R5, D2, R1, D2, DD, DD);
  // 11. outN_h = VN .NT. attNT -> R5 fp16 (attN dead)
  gemm256<5, 0><<<dim3(4, 6, 16), 512, 0, stream>>>(R4, SD, R1, D2, nullptr, 0,
                                                    (void*)R5, SD, nullptr, SS, DD, DD);

  // 12. gate, gated pooling, combine, FC
  gate_k<<<4096, 256, 0, stream>>>(R5, Wsg, bsg, gate);
  opool<<<dim3(32, BB), 256, 0, stream>>>(R5, gate, opart);
  pool_final<<<48, 256, 0, stream>>>(tpart, opart, pooled);
  fc_k<<<16, 256, 0, stream>>>(pooled, Wf, bfn, outp);
}